// Round 20
// baseline (572.924 us; speedup 1.0000x reference)
//
#include <hip/hip_runtime.h>
#include <math.h>

#define NN   100000
#define NE   1000000
#define CIN  128
#define COUT 64
#define BN_EPS 1e-5f
#define NB    391      // ceil(NN/256) level-1 buckets (dst>>8)
#define NBLK1 128      // blocks per branch in sort phases 1/3
#define CHUNK_E ((NE + NBLK1 - 1) / NBLK1)   // 7813
#define NT    32       // mlp2 nodes per LDS tile
#define NTILE (NN / NT)                      // 3125

// ---- workspace layout (4-byte element offsets) ----
#define Y1B_OFF    0                        // 9,600,000 uints (3 branches)
#define COL_OFF    9600000                  // 3*NE ints
#define ROWPTR_OFF 12600000                 // 3*(NN+1) ints
#define OFF_OFF    12900016                 // 3*NB*NBLK1 ints (150144)
#define W1P_OFF    13050160                 // 3*CIN*COUT floats
#define C1_OFF     (W1P_OFF + 3*CIN*COUT)
#define INSUM_OFF  (C1_OFF + 3*COUT)
#define INSQ_OFF   (INSUM_OFF + CIN)
#define OSUM_OFF   (INSQ_OFF + CIN)
#define OSQ_OFF    (OSUM_OFF + 3*COUT)
#define SCALE_OFF  (OSQ_OFF + 3*COUT)
#define SHIFT_OFF  (SCALE_OFF + CIN)
#define OBNS_OFF   (SHIFT_OFF + CIN)
#define OBNB_OFF   (OBNS_OFF + 3*COUT)
#define ZERO_OFF   INSUM_OFF
#define ZERO_CNT   (2*CIN + 6*COUT)         // 640 floats

__device__ __forceinline__ unsigned bf16_rne(float f) {
    unsigned u = __float_as_uint(f);
    return (u + 0x7FFFu + ((u >> 16) & 1u)) >> 16;
}
__device__ __forceinline__ float lo16f(unsigned u) { return __uint_as_float(u << 16); }
__device__ __forceinline__ float hi16f(unsigned u) { return __uint_as_float(u & 0xFFFF0000u); }

// ---- input BN: per-channel sum/sumsq over nodes ----
__global__ __launch_bounds__(256) void k_in_stats(const float* __restrict__ x,
                                                  float* __restrict__ ws) {
    int tid = blockIdx.x * blockDim.x + threadIdx.x;
    int c = tid & (CIN - 1);
    int r0 = tid >> 7;
    int rstride = (gridDim.x * blockDim.x) >> 7;
    float s = 0.f, ss = 0.f;
    for (int r = r0; r < NN; r += rstride) {
        float v = x[(size_t)r * CIN + c];
        s += v; ss += v * v;
    }
    unsafeAtomicAdd(&ws[INSUM_OFF + c], s);
    unsafeAtomicAdd(&ws[INSQ_OFF + c], ss);
}

__global__ void k_in_finalize(const float* __restrict__ g, const float* __restrict__ b,
                              float* __restrict__ ws) {
    int c = threadIdx.x;   // 128 threads
    float mu  = ws[INSUM_OFF + c] * (1.f / NN);
    float var = ws[INSQ_OFF + c] * (1.f / NN) - mu * mu;
    float sc  = g[c] * rsqrtf(var + BN_EPS);
    ws[SCALE_OFF + c] = sc;
    ws[SHIFT_OFF + c] = b[c] - mu * sc;
}

// fold input-BN scale into W1:  W1'[i][k][o] = scale[k]*W1[i][k][o]
__global__ void k_fold(const float* __restrict__ W1, float* __restrict__ ws) {
    int idx = blockIdx.x * blockDim.x + threadIdx.x;   // < 3*128*64
    int k = (idx >> 6) & (CIN - 1);
    ws[W1P_OFF + idx] = ws[SCALE_OFF + k] * W1[idx];
}

// c1[i][o] = sum_k shift[k]*W1[i][k][o]
__global__ void k_c1(const float* __restrict__ W1, float* __restrict__ ws) {
    int i = blockIdx.x, o = threadIdx.x;   // 3 blocks x 64
    float acc = 0.f;
    for (int k = 0; k < CIN; ++k)
        acc = fmaf(ws[SHIFT_OFF + k], W1[i * CIN * COUT + k * COUT + o], acc);
    ws[C1_OFF + i * COUT + o] = acc;
}

// ---- two-level bucket sort of edges by dst (blockIdx.y = branch) ----
__global__ __launch_bounds__(256) void k_sort_hist(const int* __restrict__ e0,
                                                   const int* __restrict__ e1,
                                                   const int* __restrict__ e2,
                                                   int* __restrict__ wsi) {
    int z = blockIdx.y;
    const int* ei = (z == 0) ? e0 : (z == 1) ? e1 : e2;
    __shared__ int h[NB];
    for (int i = threadIdx.x; i < NB; i += 256) h[i] = 0;
    __syncthreads();
    int beg = blockIdx.x * CHUNK_E;
    int end = min(NE, beg + CHUNK_E);
    for (int e = beg + threadIdx.x; e < end; e += 256)
        atomicAdd(&h[ei[NE + e] >> 8], 1);
    __syncthreads();
    int* off = wsi + OFF_OFF + z * (NB * NBLK1);
    for (int i = threadIdx.x; i < NB; i += 256)
        off[i * NBLK1 + blockIdx.x] = h[i];
}

__global__ __launch_bounds__(1024) void k_sort_scan(int* __restrict__ wsi) {
    int z = blockIdx.x;
    int* off = wsi + OFF_OFF + z * (NB * NBLK1);
    const int TOT = NB * NBLK1;              // 50048
    const int CH = (TOT + 1023) / 1024;      // 49
    __shared__ int sh[1024];
    int t = threadIdx.x;
    int base = t * CH;
    int s = 0;
    for (int i = 0; i < CH; ++i) {
        int idx = base + i;
        if (idx < TOT) s += off[idx];
    }
    sh[t] = s;
    __syncthreads();
    for (int o = 1; o < 1024; o <<= 1) {
        int v = (t >= o) ? sh[t - o] : 0;
        __syncthreads();
        sh[t] += v;
        __syncthreads();
    }
    int run = sh[t] - s;
    for (int i = 0; i < CH; ++i) {
        int idx = base + i;
        if (idx < TOT) {
            int v = off[idx];
            off[idx] = run;
            run += v;
        }
    }
}

// phase 3: scatter edges into bucket-contiguous temp, PACKED one word/edge:
// (dst&255)<<24 | src   (src < 2^17 fits in 24 bits)
__global__ __launch_bounds__(256) void k_sort_scatter(const int* __restrict__ e0,
                                                      const int* __restrict__ e1,
                                                      const int* __restrict__ e2,
                                                      int* __restrict__ wsi) {
    int z = blockIdx.y;
    const int* ei = (z == 0) ? e0 : (z == 1) ? e1 : e2;
    const int* off = wsi + OFF_OFF + z * (NB * NBLK1);
    unsigned* temp = (unsigned*)wsi + (size_t)z * NE;
    __shared__ int cur[NB];
    for (int i = threadIdx.x; i < NB; i += 256)
        cur[i] = off[i * NBLK1 + blockIdx.x];
    __syncthreads();
    int beg = blockIdx.x * CHUNK_E;
    int end = min(NE, beg + CHUNK_E);
    for (int e = beg + threadIdx.x; e < end; e += 256) {
        int d = ei[NE + e];
        int s = ei[e];
        int pos = atomicAdd(&cur[d >> 8], 1);
        temp[pos] = ((unsigned)(d & 255) << 24) | (unsigned)s;
    }
}

__global__ __launch_bounds__(256) void k_bucket(int* __restrict__ wsi) {
    int z = blockIdx.y, bk = blockIdx.x;
    const int* off = wsi + OFF_OFF + z * (NB * NBLK1);
    const unsigned* temp = (const unsigned*)wsi + (size_t)z * NE;
    int* col    = wsi + COL_OFF + z * NE;
    int* rowptr = wsi + ROWPTR_OFF + z * (NN + 1);
    int bs = off[bk * NBLK1];
    int be = (bk + 1 < NB) ? off[(bk + 1) * NBLK1] : NE;
    __shared__ int h[256], sc[256], cur[256];
    int t = threadIdx.x;
    h[t] = 0;
    __syncthreads();
    for (int e = bs + t; e < be; e += 256)
        atomicAdd(&h[temp[e] >> 24], 1);
    __syncthreads();
    int v = h[t];
    sc[t] = v;
    __syncthreads();
    for (int o = 1; o < 256; o <<= 1) {
        int u = (t >= o) ? sc[t - o] : 0;
        __syncthreads();
        sc[t] += u;
        __syncthreads();
    }
    int excl = sc[t] - v;
    int gd = bk * 256 + t;
    if (gd <= NN) rowptr[gd] = bs + excl;   // gd==NN lands on empty tail -> NE
    cur[t] = excl;
    __syncthreads();
    for (int e = bs + t; e < be; e += 256) {
        unsigned p = temp[e];
        int pos = atomicAdd(&cur[p >> 24], 1);
        col[bs + pos] = (int)(p & 0x00FFFFFFu);
    }
}

// y1b for ALL 3 branches in one pass; 16 nodes/wave-group x 16-ch chunks:
// 48 weight loads feed 768 FMAs per chunk (1:16), x via wave-uniform s_load.
__global__ __launch_bounds__(256, 2) void k_gemm1(const float* __restrict__ x,
                                                  const float* __restrict__ W1p_all,
                                                  const float* __restrict__ c1_all,
                                                  unsigned* __restrict__ y1b_all) {
    int lane = threadIdx.x & 63;
    int wave = (blockIdx.x * blockDim.x + threadIdx.x) >> 6;
    int nw   = (gridDim.x * blockDim.x) >> 6;
    float c1v0 = c1_all[lane];
    float c1v1 = c1_all[COUT + lane];
    float c1v2 = c1_all[2 * COUT + lane];
    const int NGRP = NN / 16;   // 6250
    for (int g = wave; g < NGRP; g += nw) {
        int n0 = __builtin_amdgcn_readfirstlane(g) * 16;
        const float* __restrict__ xr = x + (size_t)n0 * CIN;
        float a0[16], a1[16], a2[16];
        #pragma unroll
        for (int i = 0; i < 16; ++i) { a0[i] = c1v0; a1[i] = c1v1; a2[i] = c1v2; }
        #pragma unroll 1
        for (int kc = 0; kc < CIN; kc += 16) {
            float w0[16], w1[16], w2[16];
            #pragma unroll
            for (int j = 0; j < 16; ++j) {
                w0[j] = W1p_all[(kc + j) * COUT + lane];
                w1[j] = W1p_all[CIN * COUT + (kc + j) * COUT + lane];
                w2[j] = W1p_all[2 * CIN * COUT + (kc + j) * COUT + lane];
            }
            #pragma unroll
            for (int i = 0; i < 16; ++i) {
                #pragma unroll
                for (int j = 0; j < 16; ++j) {
                    float xv = xr[i * CIN + kc + j];
                    a0[i] = fmaf(xv, w0[j], a0[i]);
                    a1[i] = fmaf(xv, w1[j], a1[i]);
                    a2[i] = fmaf(xv, w2[j], a2[i]);
                }
            }
        }
        #define STORE_NODE(zz, az, i) { \
            float vhi_ = __shfl(az[i], (lane & 31) + 32); \
            if (lane < 32) { \
                unsigned wrd_ = bf16_rne(az[i]) | (bf16_rne(vhi_) << 16); \
                y1b_all[((size_t)(zz) * NN + n0 + (i)) * 32 + lane] = wrd_; \
            } }
        #pragma unroll
        for (int i = 0; i < 16; ++i) {
            STORE_NODE(0, a0, i)
            STORE_NODE(1, a1, i)
            STORE_NODE(2, a2, i)
        }
        #undef STORE_NODE
    }
}

// aggregation + layer-1 epilogue, QUARTER-WAVE per node (16 lanes x uint2).
__global__ __launch_bounds__(256) void k_gather(const float* __restrict__ b1all,
                                                float* __restrict__ tall,
                                                float* __restrict__ ws) {
    int z = blockIdx.y;
    const uint2* __restrict__ y2 =
        (const uint2*)((const unsigned*)ws + Y1B_OFF + (size_t)z * NN * 32);
    float* __restrict__ t = tall + (size_t)z * NN * COUT;
    const int* __restrict__ rowptr = (const int*)ws + ROWPTR_OFF + z * (NN + 1);
    const int* __restrict__ col    = (const int*)ws + COL_OFF + z * NE;
    int lane = threadIdx.x & 63;
    int q = lane & 15;
    int quarter = lane >> 4;
    float b1a = b1all[z * COUT + 2 * q];
    float b1b = b1all[z * COUT + 2 * q + 1];
    float b1c = b1all[z * COUT + 32 + 2 * q];
    float b1d = b1all[z * COUT + 33 + 2 * q];
    int wave = (blockIdx.x * blockDim.x + threadIdx.x) >> 6;
    int nw   = (gridDim.x * blockDim.x) >> 6;
    const int NG = NN / 4;   // 25000 groups of 4 nodes
    for (int g = wave; g < NG; g += nw) {
        int n = g * 4 + quarter;
        int beg = rowptr[n], end = rowptr[n + 1];
        uint2 su = y2[(size_t)n * 16 + q];
        float aa = lo16f(su.x), ab = hi16f(su.x);
        float ac = lo16f(su.y), ad = hi16f(su.y);
        float ba = 0.f, bb = 0.f, bc = 0.f, bd = 0.f;
        float ca = 0.f, cb = 0.f, cc = 0.f, cd = 0.f;
        float da = 0.f, db = 0.f, dc = 0.f, dd = 0.f;
        int j = beg;
        for (; j + 3 < end; j += 4) {
            int c0 = col[j], c1 = col[j + 1], c2 = col[j + 2], c3 = col[j + 3];
            uint2 u0 = y2[(size_t)c0 * 16 + q];
            uint2 u1 = y2[(size_t)c1 * 16 + q];
            uint2 u2 = y2[(size_t)c2 * 16 + q];
            uint2 u3 = y2[(size_t)c3 * 16 + q];
            aa += lo16f(u0.x); ab += hi16f(u0.x); ac += lo16f(u0.y); ad += hi16f(u0.y);
            ba += lo16f(u1.x); bb += hi16f(u1.x); bc += lo16f(u1.y); bd += hi16f(u1.y);
            ca += lo16f(u2.x); cb += hi16f(u2.x); cc += lo16f(u2.y); cd += hi16f(u2.y);
            da += lo16f(u3.x); db += hi16f(u3.x); dc += lo16f(u3.y); dd += hi16f(u3.y);
        }
        for (; j < end; ++j) {
            uint2 u = y2[(size_t)col[j] * 16 + q];
            aa += lo16f(u.x); ab += hi16f(u.x); ac += lo16f(u.y); ad += hi16f(u.y);
        }
        float2 lo = make_float2(fmaxf((aa + ba) + (ca + da) + b1a, 0.f),
                                fmaxf((ac + bc) + (cc + dc) + b1b, 0.f));
        float2 hi = make_float2(fmaxf((ab + bb) + (cb + db) + b1c, 0.f),
                                fmaxf((ad + bd) + (cd + dd) + b1d, 0.f));
        *(float2*)(t + (size_t)n * 64 + 2 * q)      = lo;
        *(float2*)(t + (size_t)n * 64 + 32 + 2 * q) = hi;
    }
}

// MLP2 in-place on d_out, PERSISTENT blocks (best measured variant):
// W2 in LDS once per block; grid-stride over 32-node tiles {stage tile to
// LDS coalesced, compute 8 nodes/wave from LDS}. BN stats in registers.
__global__ __launch_bounds__(256) void k_mlp2(const float* __restrict__ W2all,
                                              const float* __restrict__ b2all,
                                              float* __restrict__ outall,
                                              float* __restrict__ ws) {
    int z = blockIdx.y;
    __shared__ float w2s[COUT * COUT];   // 16 KB
    __shared__ float ts[NT][COUT];       // 8 KB
    const float* __restrict__ W2 = W2all + z * COUT * COUT;
    float* __restrict__ out = outall + (size_t)z * NN * COUT;
    int tid = threadIdx.x;
    for (int i = tid; i < COUT * COUT; i += 256) w2s[i] = W2[i];
    int lane = tid & 63;
    int wave = tid >> 6;                 // 0..3
    int n0 = wave * 8;
    float b2v = b2all[z * COUT + lane];
    float ls = 0.f, lss = 0.f;
    for (int tile = blockIdx.x; tile < NTILE; tile += gridDim.x) {
        __syncthreads();   // ts safe to overwrite (covers w2s on iter 0)
        {
            const float4* __restrict__ src =
                (const float4*)(out + (size_t)tile * NT * COUT);
            float4* dst = (float4*)ts;
            dst[tid] = src[tid];
            dst[tid + 256] = src[tid + 256];
        }
        __syncthreads();
        float a0 = b2v, a1 = b2v, a2 = b2v, a3 = b2v;
        float a4 = b2v, a5 = b2v, a6 = b2v, a7 = b2v;
        #pragma unroll
        for (int jq = 0; jq < 16; ++jq) {
            float wj0 = w2s[(4 * jq)     * COUT + lane];
            float wj1 = w2s[(4 * jq + 1) * COUT + lane];
            float wj2 = w2s[(4 * jq + 2) * COUT + lane];
            float wj3 = w2s[(4 * jq + 3) * COUT + lane];
            float4 t0 = *(const float4*)&ts[n0 + 0][4 * jq];
            float4 t1 = *(const float4*)&ts[n0 + 1][4 * jq];
            float4 t2 = *(const float4*)&ts[n0 + 2][4 * jq];
            float4 t3 = *(const float4*)&ts[n0 + 3][4 * jq];
            float4 t4 = *(const float4*)&ts[n0 + 4][4 * jq];
            float4 t5 = *(const float4*)&ts[n0 + 5][4 * jq];
            float4 t6 = *(const float4*)&ts[n0 + 6][4 * jq];
            float4 t7 = *(const float4*)&ts[n0 + 7][4 * jq];
            a0 = fmaf(t0.x, wj0, a0); a0 = fmaf(t0.y, wj1, a0);
            a0 = fmaf(t0.z, wj2, a0); a0 = fmaf(t0.w, wj3, a0);
            a1 = fmaf(t1.x, wj0, a1); a1 = fmaf(t1.y, wj1, a1);
            a1 = fmaf(t1.z, wj2, a1); a1 = fmaf(t1.w, wj3, a1);
            a2 = fmaf(t2.x, wj0, a2); a2 = fmaf(t2.y, wj1, a2);
            a2 = fmaf(t2.z, wj2, a2); a2 = fmaf(t2.w, wj3, a2);
            a3 = fmaf(t3.x, wj0, a3); a3 = fmaf(t3.y, wj1, a3);
            a3 = fmaf(t3.z, wj2, a3); a3 = fmaf(t3.w, wj3, a3);
            a4 = fmaf(t4.x, wj0, a4); a4 = fmaf(t4.y, wj1, a4);
            a4 = fmaf(t4.z, wj2, a4); a4 = fmaf(t4.w, wj3, a4);
            a5 = fmaf(t5.x, wj0, a5); a5 = fmaf(t5.y, wj1, a5);
            a5 = fmaf(t5.z, wj2, a5); a5 = fmaf(t5.w, wj3, a5);
            a6 = fmaf(t6.x, wj0, a6); a6 = fmaf(t6.y, wj1, a6);
            a6 = fmaf(t6.z, wj2, a6); a6 = fmaf(t6.w, wj3, a6);
            a7 = fmaf(t7.x, wj0, a7); a7 = fmaf(t7.y, wj1, a7);
            a7 = fmaf(t7.z, wj2, a7); a7 = fmaf(t7.w, wj3, a7);
        }
        size_t base = (size_t)tile * NT * COUT + (size_t)n0 * COUT;
        out[base + lane] = a0;
        out[base + COUT + lane] = a1;
        out[base + 2 * COUT + lane] = a2;
        out[base + 3 * COUT + lane] = a3;
        out[base + 4 * COUT + lane] = a4;
        out[base + 5 * COUT + lane] = a5;
        out[base + 6 * COUT + lane] = a6;
        out[base + 7 * COUT + lane] = a7;
        ls += ((a0 + a1) + (a2 + a3)) + ((a4 + a5) + (a6 + a7));
        lss += ((a0 * a0 + a1 * a1) + (a2 * a2 + a3 * a3))
             + ((a4 * a4 + a5 * a5) + (a6 * a6 + a7 * a7));
    }
    unsafeAtomicAdd(&ws[OSUM_OFF + z * COUT + lane], ls);
    unsafeAtomicAdd(&ws[OSQ_OFF + z * COUT + lane], lss);
}

__global__ void k_obn_final(const float* __restrict__ g, const float* __restrict__ b,
                            float* __restrict__ ws) {
    int br = blockIdx.x;   // 3 blocks x 64
    int o = threadIdx.x;
    float mu  = ws[OSUM_OFF + br * COUT + o] * (1.f / NN);
    float var = ws[OSQ_OFF  + br * COUT + o] * (1.f / NN) - mu * mu;
    float sc  = g[br * COUT + o] * rsqrtf(var + BN_EPS);
    ws[OBNS_OFF + br * COUT + o] = sc;
    ws[OBNB_OFF + br * COUT + o] = b[br * COUT + o] - mu * sc;
}

// y = tanh(sc[c]*h2 + sh[c]) in-place; blockIdx.y = branch
__global__ __launch_bounds__(256) void k_apply(float* __restrict__ outall,
                                               const float* __restrict__ ws) {
    int z = blockIdx.y;
    float* out = outall + (size_t)z * NN * COUT;
    const float* __restrict__ sc = ws + OBNS_OFF + z * COUT;
    const float* __restrict__ sh = ws + OBNB_OFF + z * COUT;
    int idx = blockIdx.x * blockDim.x + threadIdx.x;
    int stride = gridDim.x * blockDim.x;
    const int total = NN * COUT / 4;
    float4* o4 = (float4*)out;
    for (int v = idx; v < total; v += stride) {
        int c = (v & 15) * 4;
        float4 f = o4[v];
        f.x = tanhf(fmaf(f.x, sc[c],     sh[c]));
        f.y = tanhf(fmaf(f.y, sc[c + 1], sh[c + 1]));
        f.z = tanhf(fmaf(f.z, sc[c + 2], sh[c + 2]));
        f.w = tanhf(fmaf(f.w, sc[c + 3], sh[c + 3]));
        o4[v] = f;
    }
}

extern "C" void kernel_launch(void* const* d_in, const int* in_sizes, int n_in,
                              void* d_out, int out_size, void* d_ws, size_t ws_size,
                              hipStream_t stream) {
    const float* x   = (const float*)d_in[0];
    const int*   eip = (const int*)d_in[1];
    const int*   eis = (const int*)d_in[2];
    const int*   eiv = (const int*)d_in[3];
    const float* ig  = (const float*)d_in[4];
    const float* ib  = (const float*)d_in[5];
    const float* W1  = (const float*)d_in[6];
    const float* b1  = (const float*)d_in[7];
    const float* W2  = (const float*)d_in[8];
    const float* b2  = (const float*)d_in[9];
    const float* bng = (const float*)d_in[10];
    const float* bnb = (const float*)d_in[11];
    float* out = (float*)d_out;
    float* ws  = (float*)d_ws;
    int*   wsi = (int*)d_ws;

    hipMemsetAsync(ws + ZERO_OFF, 0, ZERO_CNT * sizeof(float), stream);

    k_in_stats<<<256, 256, 0, stream>>>(x, ws);
    k_in_finalize<<<1, 128, 0, stream>>>(ig, ib, ws);
    k_fold<<<96, 256, 0, stream>>>(W1, ws);
    k_c1<<<3, 64, 0, stream>>>(W1, ws);

    // two-level bucket sort -> CSR for all 3 branches (temp overlaps y1b3;
    // all sort kernels complete before k_gemm1)
    k_sort_hist<<<dim3(NBLK1, 3), 256, 0, stream>>>(eip, eis, eiv, wsi);
    k_sort_scan<<<3, 1024, 0, stream>>>(wsi);
    k_sort_scatter<<<dim3(NBLK1, 3), 256, 0, stream>>>(eip, eis, eiv, wsi);
    k_bucket<<<dim3(NB, 3), 256, 0, stream>>>(wsi);

    // gemm1: single pass over x computes all 3 branches
    k_gemm1<<<1024, 256, 0, stream>>>(x, ws + W1P_OFF, ws + C1_OFF,
                                      (unsigned*)ws + Y1B_OFF);
    k_gather<<<dim3(2048, 3), 256, 0, stream>>>(b1, out, ws);
    k_mlp2<<<dim3(512, 3), 256, 0, stream>>>(W2, b2, out, ws);
    k_obn_final<<<3, 64, 0, stream>>>(bng, bnb, ws);
    k_apply<<<dim3(1024, 3), 256, 0, stream>>>(out, ws);
}

// Round 21
// 507.153 us; speedup vs baseline: 1.1297x; 1.1297x over previous
//
#include <hip/hip_runtime.h>
#include <math.h>

#define NN   100000
#define NE   1000000
#define CIN  128
#define COUT 64
#define BN_EPS 1e-5f
#define NB    391      // ceil(NN/256) level-1 buckets (dst>>8)
#define NBLK1 128      // blocks per branch in sort phases 1/3
#define CHUNK_E ((NE + NBLK1 - 1) / NBLK1)   // 7813
#define NT    32       // mlp2 nodes per LDS tile
#define NTILE (NN / NT)                      // 3125

// ---- workspace layout (4-byte element offsets) ----
#define Y1B_OFF    0                        // 9,600,000 uints (3 branches)
#define COL_OFF    9600000                  // 3*NE ints
#define ROWPTR_OFF 12600000                 // 3*(NN+1) ints
#define OFF_OFF    12900016                 // 3*NB*NBLK1 ints (150144)
#define W1P_OFF    13050160                 // 3*CIN*COUT floats
#define C1_OFF     (W1P_OFF + 3*CIN*COUT)
#define INSUM_OFF  (C1_OFF + 3*COUT)
#define INSQ_OFF   (INSUM_OFF + CIN)
#define OSUM_OFF   (INSQ_OFF + CIN)
#define OSQ_OFF    (OSUM_OFF + 3*COUT)
#define SCALE_OFF  (OSQ_OFF + 3*COUT)
#define SHIFT_OFF  (SCALE_OFF + CIN)
#define ZERO_OFF   INSUM_OFF
#define ZERO_CNT   (2*CIN + 6*COUT)         // 640 floats

__device__ __forceinline__ unsigned bf16_rne(float f) {
    unsigned u = __float_as_uint(f);
    return (u + 0x7FFFu + ((u >> 16) & 1u)) >> 16;
}
__device__ __forceinline__ float lo16f(unsigned u) { return __uint_as_float(u << 16); }
__device__ __forceinline__ float hi16f(unsigned u) { return __uint_as_float(u & 0xFFFF0000u); }

// ---- input BN: per-channel sum/sumsq over nodes ----
__global__ __launch_bounds__(256) void k_in_stats(const float* __restrict__ x,
                                                  float* __restrict__ ws) {
    int tid = blockIdx.x * blockDim.x + threadIdx.x;
    int c = tid & (CIN - 1);
    int r0 = tid >> 7;
    int rstride = (gridDim.x * blockDim.x) >> 7;
    float s = 0.f, ss = 0.f;
    for (int r = r0; r < NN; r += rstride) {
        float v = x[(size_t)r * CIN + c];
        s += v; ss += v * v;
    }
    unsafeAtomicAdd(&ws[INSUM_OFF + c], s);
    unsafeAtomicAdd(&ws[INSQ_OFF + c], ss);
}

__global__ void k_in_finalize(const float* __restrict__ g, const float* __restrict__ b,
                              float* __restrict__ ws) {
    int c = threadIdx.x;   // 128 threads
    float mu  = ws[INSUM_OFF + c] * (1.f / NN);
    float var = ws[INSQ_OFF + c] * (1.f / NN) - mu * mu;
    float sc  = g[c] * rsqrtf(var + BN_EPS);
    ws[SCALE_OFF + c] = sc;
    ws[SHIFT_OFF + c] = b[c] - mu * sc;
}

// fold input-BN scale into W1:  W1'[i][k][o] = scale[k]*W1[i][k][o]
__global__ void k_fold(const float* __restrict__ W1, float* __restrict__ ws) {
    int idx = blockIdx.x * blockDim.x + threadIdx.x;   // < 3*128*64
    int k = (idx >> 6) & (CIN - 1);
    ws[W1P_OFF + idx] = ws[SCALE_OFF + k] * W1[idx];
}

// c1[i][o] = sum_k shift[k]*W1[i][k][o]
__global__ void k_c1(const float* __restrict__ W1, float* __restrict__ ws) {
    int i = blockIdx.x, o = threadIdx.x;   // 3 blocks x 64
    float acc = 0.f;
    for (int k = 0; k < CIN; ++k)
        acc = fmaf(ws[SHIFT_OFF + k], W1[i * CIN * COUT + k * COUT + o], acc);
    ws[C1_OFF + i * COUT + o] = acc;
}

// ---- two-level bucket sort of edges by dst (blockIdx.y = branch) ----
__global__ __launch_bounds__(256) void k_sort_hist(const int* __restrict__ e0,
                                                   const int* __restrict__ e1,
                                                   const int* __restrict__ e2,
                                                   int* __restrict__ wsi) {
    int z = blockIdx.y;
    const int* ei = (z == 0) ? e0 : (z == 1) ? e1 : e2;
    __shared__ int h[NB];
    for (int i = threadIdx.x; i < NB; i += 256) h[i] = 0;
    __syncthreads();
    int beg = blockIdx.x * CHUNK_E;
    int end = min(NE, beg + CHUNK_E);
    for (int e = beg + threadIdx.x; e < end; e += 256)
        atomicAdd(&h[ei[NE + e] >> 8], 1);
    __syncthreads();
    int* off = wsi + OFF_OFF + z * (NB * NBLK1);
    for (int i = threadIdx.x; i < NB; i += 256)
        off[i * NBLK1 + blockIdx.x] = h[i];
}

__global__ __launch_bounds__(1024) void k_sort_scan(int* __restrict__ wsi) {
    int z = blockIdx.x;
    int* off = wsi + OFF_OFF + z * (NB * NBLK1);
    const int TOT = NB * NBLK1;              // 50048
    const int CH = (TOT + 1023) / 1024;      // 49
    __shared__ int sh[1024];
    int t = threadIdx.x;
    int base = t * CH;
    int s = 0;
    for (int i = 0; i < CH; ++i) {
        int idx = base + i;
        if (idx < TOT) s += off[idx];
    }
    sh[t] = s;
    __syncthreads();
    for (int o = 1; o < 1024; o <<= 1) {
        int v = (t >= o) ? sh[t - o] : 0;
        __syncthreads();
        sh[t] += v;
        __syncthreads();
    }
    int run = sh[t] - s;
    for (int i = 0; i < CH; ++i) {
        int idx = base + i;
        if (idx < TOT) {
            int v = off[idx];
            off[idx] = run;
            run += v;
        }
    }
}

// phase 3: scatter edges into bucket-contiguous temp, PACKED one word/edge:
// (dst&255)<<24 | src   (src < 2^17 fits in 24 bits)
__global__ __launch_bounds__(256) void k_sort_scatter(const int* __restrict__ e0,
                                                      const int* __restrict__ e1,
                                                      const int* __restrict__ e2,
                                                      int* __restrict__ wsi) {
    int z = blockIdx.y;
    const int* ei = (z == 0) ? e0 : (z == 1) ? e1 : e2;
    const int* off = wsi + OFF_OFF + z * (NB * NBLK1);
    unsigned* temp = (unsigned*)wsi + (size_t)z * NE;
    __shared__ int cur[NB];
    for (int i = threadIdx.x; i < NB; i += 256)
        cur[i] = off[i * NBLK1 + blockIdx.x];
    __syncthreads();
    int beg = blockIdx.x * CHUNK_E;
    int end = min(NE, beg + CHUNK_E);
    for (int e = beg + threadIdx.x; e < end; e += 256) {
        int d = ei[NE + e];
        int s = ei[e];
        int pos = atomicAdd(&cur[d >> 8], 1);
        temp[pos] = ((unsigned)(d & 255) << 24) | (unsigned)s;
    }
}

__global__ __launch_bounds__(256) void k_bucket(int* __restrict__ wsi) {
    int z = blockIdx.y, bk = blockIdx.x;
    const int* off = wsi + OFF_OFF + z * (NB * NBLK1);
    const unsigned* temp = (const unsigned*)wsi + (size_t)z * NE;
    int* col    = wsi + COL_OFF + z * NE;
    int* rowptr = wsi + ROWPTR_OFF + z * (NN + 1);
    int bs = off[bk * NBLK1];
    int be = (bk + 1 < NB) ? off[(bk + 1) * NBLK1] : NE;
    __shared__ int h[256], sc[256], cur[256];
    int t = threadIdx.x;
    h[t] = 0;
    __syncthreads();
    for (int e = bs + t; e < be; e += 256)
        atomicAdd(&h[temp[e] >> 24], 1);
    __syncthreads();
    int v = h[t];
    sc[t] = v;
    __syncthreads();
    for (int o = 1; o < 256; o <<= 1) {
        int u = (t >= o) ? sc[t - o] : 0;
        __syncthreads();
        sc[t] += u;
        __syncthreads();
    }
    int excl = sc[t] - v;
    int gd = bk * 256 + t;
    if (gd <= NN) rowptr[gd] = bs + excl;   // gd==NN lands on empty tail -> NE
    cur[t] = excl;
    __syncthreads();
    for (int e = bs + t; e < be; e += 256) {
        unsigned p = temp[e];
        int pos = atomicAdd(&cur[p >> 24], 1);
        col[bs + pos] = (int)(p & 0x00FFFFFFu);
    }
}

// y1b for ALL 3 branches in one pass (8 nodes/wave x 16-ch chunks x 3 br)
__global__ __launch_bounds__(256, 2) void k_gemm1(const float* __restrict__ x,
                                                  const float* __restrict__ W1p_all,
                                                  const float* __restrict__ c1_all,
                                                  unsigned* __restrict__ y1b_all) {
    int lane = threadIdx.x & 63;
    int wave = (blockIdx.x * blockDim.x + threadIdx.x) >> 6;
    int nw   = (gridDim.x * blockDim.x) >> 6;
    float c1v0 = c1_all[lane];
    float c1v1 = c1_all[COUT + lane];
    float c1v2 = c1_all[2 * COUT + lane];
    const int NGRP = NN / 8;   // 12500
    for (int g = wave; g < NGRP; g += nw) {
        int n0 = __builtin_amdgcn_readfirstlane(g) * 8;
        const float* __restrict__ xr = x + (size_t)n0 * CIN;
        float a0[8], a1[8], a2[8];
        #pragma unroll
        for (int i = 0; i < 8; ++i) { a0[i] = c1v0; a1[i] = c1v1; a2[i] = c1v2; }
        #pragma unroll 1
        for (int kc = 0; kc < CIN; kc += 16) {
            float w0[16], w1[16], w2[16];
            #pragma unroll
            for (int j = 0; j < 16; ++j) {
                w0[j] = W1p_all[(kc + j) * COUT + lane];
                w1[j] = W1p_all[CIN * COUT + (kc + j) * COUT + lane];
                w2[j] = W1p_all[2 * CIN * COUT + (kc + j) * COUT + lane];
            }
            #pragma unroll
            for (int i = 0; i < 8; ++i) {
                #pragma unroll
                for (int j = 0; j < 16; ++j) {
                    float xv = xr[i * CIN + kc + j];
                    a0[i] = fmaf(xv, w0[j], a0[i]);
                    a1[i] = fmaf(xv, w1[j], a1[i]);
                    a2[i] = fmaf(xv, w2[j], a2[i]);
                }
            }
        }
        #define STORE_NODE(zz, az, i) { \
            float vhi_ = __shfl(az[i], (lane & 31) + 32); \
            if (lane < 32) { \
                unsigned wrd_ = bf16_rne(az[i]) | (bf16_rne(vhi_) << 16); \
                y1b_all[((size_t)(zz) * NN + n0 + (i)) * 32 + lane] = wrd_; \
            } }
        #pragma unroll
        for (int i = 0; i < 8; ++i) {
            STORE_NODE(0, a0, i)
            STORE_NODE(1, a1, i)
            STORE_NODE(2, a2, i)
        }
        #undef STORE_NODE
    }
}

// aggregation + layer-1 epilogue, QUARTER-WAVE per node (16 lanes x uint2).
__global__ __launch_bounds__(256) void k_gather(const float* __restrict__ b1all,
                                                float* __restrict__ tall,
                                                float* __restrict__ ws) {
    int z = blockIdx.y;
    const uint2* __restrict__ y2 =
        (const uint2*)((const unsigned*)ws + Y1B_OFF + (size_t)z * NN * 32);
    float* __restrict__ t = tall + (size_t)z * NN * COUT;
    const int* __restrict__ rowptr = (const int*)ws + ROWPTR_OFF + z * (NN + 1);
    const int* __restrict__ col    = (const int*)ws + COL_OFF + z * NE;
    int lane = threadIdx.x & 63;
    int q = lane & 15;
    int quarter = lane >> 4;
    float b1a = b1all[z * COUT + 2 * q];
    float b1b = b1all[z * COUT + 2 * q + 1];
    float b1c = b1all[z * COUT + 32 + 2 * q];
    float b1d = b1all[z * COUT + 33 + 2 * q];
    int wave = (blockIdx.x * blockDim.x + threadIdx.x) >> 6;
    int nw   = (gridDim.x * blockDim.x) >> 6;
    const int NG = NN / 4;   // 25000 groups of 4 nodes
    for (int g = wave; g < NG; g += nw) {
        int n = g * 4 + quarter;
        int beg = rowptr[n], end = rowptr[n + 1];
        uint2 su = y2[(size_t)n * 16 + q];
        float aa = lo16f(su.x), ab = hi16f(su.x);
        float ac = lo16f(su.y), ad = hi16f(su.y);
        float ba = 0.f, bb = 0.f, bc = 0.f, bd = 0.f;
        float ca = 0.f, cb = 0.f, cc = 0.f, cd = 0.f;
        float da = 0.f, db = 0.f, dc = 0.f, dd = 0.f;
        int j = beg;
        for (; j + 3 < end; j += 4) {
            int c0 = col[j], c1 = col[j + 1], c2 = col[j + 2], c3 = col[j + 3];
            uint2 u0 = y2[(size_t)c0 * 16 + q];
            uint2 u1 = y2[(size_t)c1 * 16 + q];
            uint2 u2 = y2[(size_t)c2 * 16 + q];
            uint2 u3 = y2[(size_t)c3 * 16 + q];
            aa += lo16f(u0.x); ab += hi16f(u0.x); ac += lo16f(u0.y); ad += hi16f(u0.y);
            ba += lo16f(u1.x); bb += hi16f(u1.x); bc += lo16f(u1.y); bd += hi16f(u1.y);
            ca += lo16f(u2.x); cb += hi16f(u2.x); cc += lo16f(u2.y); cd += hi16f(u2.y);
            da += lo16f(u3.x); db += hi16f(u3.x); dc += lo16f(u3.y); dd += hi16f(u3.y);
        }
        for (; j < end; ++j) {
            uint2 u = y2[(size_t)col[j] * 16 + q];
            aa += lo16f(u.x); ab += hi16f(u.x); ac += lo16f(u.y); ad += hi16f(u.y);
        }
        float2 lo = make_float2(fmaxf((aa + ba) + (ca + da) + b1a, 0.f),
                                fmaxf((ac + bc) + (cc + dc) + b1b, 0.f));
        float2 hi = make_float2(fmaxf((ab + bb) + (cb + db) + b1c, 0.f),
                                fmaxf((ad + bd) + (cd + dd) + b1d, 0.f));
        *(float2*)(t + (size_t)n * 64 + 2 * q)      = lo;
        *(float2*)(t + (size_t)n * 64 + 32 + 2 * q) = hi;
    }
}

// MLP2 in-place on d_out, PERSISTENT blocks (best measured variant):
// W2 in LDS once per block; grid-stride over 32-node tiles {stage tile to
// LDS coalesced, compute 8 nodes/wave from LDS}. BN stats in registers.
__global__ __launch_bounds__(256) void k_mlp2(const float* __restrict__ W2all,
                                              const float* __restrict__ b2all,
                                              float* __restrict__ outall,
                                              float* __restrict__ ws) {
    int z = blockIdx.y;
    __shared__ float w2s[COUT * COUT];   // 16 KB
    __shared__ float ts[NT][COUT];       // 8 KB
    const float* __restrict__ W2 = W2all + z * COUT * COUT;
    float* __restrict__ out = outall + (size_t)z * NN * COUT;
    int tid = threadIdx.x;
    for (int i = tid; i < COUT * COUT; i += 256) w2s[i] = W2[i];
    int lane = tid & 63;
    int wave = tid >> 6;                 // 0..3
    int n0 = wave * 8;
    float b2v = b2all[z * COUT + lane];
    float ls = 0.f, lss = 0.f;
    for (int tile = blockIdx.x; tile < NTILE; tile += gridDim.x) {
        __syncthreads();   // ts safe to overwrite (covers w2s on iter 0)
        {
            const float4* __restrict__ src =
                (const float4*)(out + (size_t)tile * NT * COUT);
            float4* dst = (float4*)ts;
            dst[tid] = src[tid];
            dst[tid + 256] = src[tid + 256];
        }
        __syncthreads();
        float a0 = b2v, a1 = b2v, a2 = b2v, a3 = b2v;
        float a4 = b2v, a5 = b2v, a6 = b2v, a7 = b2v;
        #pragma unroll
        for (int jq = 0; jq < 16; ++jq) {
            float wj0 = w2s[(4 * jq)     * COUT + lane];
            float wj1 = w2s[(4 * jq + 1) * COUT + lane];
            float wj2 = w2s[(4 * jq + 2) * COUT + lane];
            float wj3 = w2s[(4 * jq + 3) * COUT + lane];
            float4 t0 = *(const float4*)&ts[n0 + 0][4 * jq];
            float4 t1 = *(const float4*)&ts[n0 + 1][4 * jq];
            float4 t2 = *(const float4*)&ts[n0 + 2][4 * jq];
            float4 t3 = *(const float4*)&ts[n0 + 3][4 * jq];
            float4 t4 = *(const float4*)&ts[n0 + 4][4 * jq];
            float4 t5 = *(const float4*)&ts[n0 + 5][4 * jq];
            float4 t6 = *(const float4*)&ts[n0 + 6][4 * jq];
            float4 t7 = *(const float4*)&ts[n0 + 7][4 * jq];
            a0 = fmaf(t0.x, wj0, a0); a0 = fmaf(t0.y, wj1, a0);
            a0 = fmaf(t0.z, wj2, a0); a0 = fmaf(t0.w, wj3, a0);
            a1 = fmaf(t1.x, wj0, a1); a1 = fmaf(t1.y, wj1, a1);
            a1 = fmaf(t1.z, wj2, a1); a1 = fmaf(t1.w, wj3, a1);
            a2 = fmaf(t2.x, wj0, a2); a2 = fmaf(t2.y, wj1, a2);
            a2 = fmaf(t2.z, wj2, a2); a2 = fmaf(t2.w, wj3, a2);
            a3 = fmaf(t3.x, wj0, a3); a3 = fmaf(t3.y, wj1, a3);
            a3 = fmaf(t3.z, wj2, a3); a3 = fmaf(t3.w, wj3, a3);
            a4 = fmaf(t4.x, wj0, a4); a4 = fmaf(t4.y, wj1, a4);
            a4 = fmaf(t4.z, wj2, a4); a4 = fmaf(t4.w, wj3, a4);
            a5 = fmaf(t5.x, wj0, a5); a5 = fmaf(t5.y, wj1, a5);
            a5 = fmaf(t5.z, wj2, a5); a5 = fmaf(t5.w, wj3, a5);
            a6 = fmaf(t6.x, wj0, a6); a6 = fmaf(t6.y, wj1, a6);
            a6 = fmaf(t6.z, wj2, a6); a6 = fmaf(t6.w, wj3, a6);
            a7 = fmaf(t7.x, wj0, a7); a7 = fmaf(t7.y, wj1, a7);
            a7 = fmaf(t7.z, wj2, a7); a7 = fmaf(t7.w, wj3, a7);
        }
        size_t base = (size_t)tile * NT * COUT + (size_t)n0 * COUT;
        out[base + lane] = a0;
        out[base + COUT + lane] = a1;
        out[base + 2 * COUT + lane] = a2;
        out[base + 3 * COUT + lane] = a3;
        out[base + 4 * COUT + lane] = a4;
        out[base + 5 * COUT + lane] = a5;
        out[base + 6 * COUT + lane] = a6;
        out[base + 7 * COUT + lane] = a7;
        ls += ((a0 + a1) + (a2 + a3)) + ((a4 + a5) + (a6 + a7));
        lss += ((a0 * a0 + a1 * a1) + (a2 * a2 + a3 * a3))
             + ((a4 * a4 + a5 * a5) + (a6 * a6 + a7 * a7));
    }
    unsafeAtomicAdd(&ws[OSUM_OFF + z * COUT + lane], ls);
    unsafeAtomicAdd(&ws[OSQ_OFF + z * COUT + lane], lss);
}

// y = tanh(sc[c]*h2 + sh[c]) in-place; blockIdx.y = branch.
// scale/shift recomputed per block from OSUM/OSQ (folds k_obn_final away).
__global__ __launch_bounds__(256) void k_apply(const float* __restrict__ g,
                                               const float* __restrict__ b,
                                               float* __restrict__ outall,
                                               const float* __restrict__ ws) {
    int z = blockIdx.y;
    float* out = outall + (size_t)z * NN * COUT;
    __shared__ float scs[COUT], shs[COUT];
    if (threadIdx.x < COUT) {
        int o = threadIdx.x;
        float mu  = ws[OSUM_OFF + z * COUT + o] * (1.f / NN);
        float var = ws[OSQ_OFF  + z * COUT + o] * (1.f / NN) - mu * mu;
        float sc  = g[z * COUT + o] * rsqrtf(var + BN_EPS);
        scs[o] = sc;
        shs[o] = b[z * COUT + o] - mu * sc;
    }
    __syncthreads();
    int idx = blockIdx.x * blockDim.x + threadIdx.x;
    int stride = gridDim.x * blockDim.x;
    const int total = NN * COUT / 4;
    float4* o4 = (float4*)out;
    for (int v = idx; v < total; v += stride) {
        int c = (v & 15) * 4;
        float4 f = o4[v];
        f.x = tanhf(fmaf(f.x, scs[c],     shs[c]));
        f.y = tanhf(fmaf(f.y, scs[c + 1], shs[c + 1]));
        f.z = tanhf(fmaf(f.z, scs[c + 2], shs[c + 2]));
        f.w = tanhf(fmaf(f.w, scs[c + 3], shs[c + 3]));
        o4[v] = f;
    }
}

extern "C" void kernel_launch(void* const* d_in, const int* in_sizes, int n_in,
                              void* d_out, int out_size, void* d_ws, size_t ws_size,
                              hipStream_t stream) {
    const float* x   = (const float*)d_in[0];
    const int*   eip = (const int*)d_in[1];
    const int*   eis = (const int*)d_in[2];
    const int*   eiv = (const int*)d_in[3];
    const float* ig  = (const float*)d_in[4];
    const float* ib  = (const float*)d_in[5];
    const float* W1  = (const float*)d_in[6];
    const float* b1  = (const float*)d_in[7];
    const float* W2  = (const float*)d_in[8];
    const float* b2  = (const float*)d_in[9];
    const float* bng = (const float*)d_in[10];
    const float* bnb = (const float*)d_in[11];
    float* out = (float*)d_out;
    float* ws  = (float*)d_ws;
    int*   wsi = (int*)d_ws;

    hipMemsetAsync(ws + ZERO_OFF, 0, ZERO_CNT * sizeof(float), stream);

    k_in_stats<<<256, 256, 0, stream>>>(x, ws);
    k_in_finalize<<<1, 128, 0, stream>>>(ig, ib, ws);
    k_fold<<<96, 256, 0, stream>>>(W1, ws);
    k_c1<<<3, 64, 0, stream>>>(W1, ws);

    // two-level bucket sort -> CSR for all 3 branches (temp overlaps y1b3;
    // all sort kernels complete before k_gemm1)
    k_sort_hist<<<dim3(NBLK1, 3), 256, 0, stream>>>(eip, eis, eiv, wsi);
    k_sort_scan<<<3, 1024, 0, stream>>>(wsi);
    k_sort_scatter<<<dim3(NBLK1, 3), 256, 0, stream>>>(eip, eis, eiv, wsi);
    k_bucket<<<dim3(NB, 3), 256, 0, stream>>>(wsi);

    // gemm1: single pass over x computes all 3 branches
    k_gemm1<<<1024, 256, 0, stream>>>(x, ws + W1P_OFF, ws + C1_OFF,
                                      (unsigned*)ws + Y1B_OFF);
    k_gather<<<dim3(2048, 3), 256, 0, stream>>>(b1, out, ws);
    k_mlp2<<<dim3(512, 3), 256, 0, stream>>>(W2, b2, out, ws);
    k_apply<<<dim3(1024, 3), 256, 0, stream>>>(bng, bnb, out, ws);
}